// Round 1
// baseline (121.859 us; speedup 1.0000x reference)
//
#include <hip/hip_runtime.h>

#define NC 20
#define STRIDE 21          // 21 (odd) -> per-thread LDS rows spread across all 32 banks
#define THREADS 256
#define BLOCKS 2048
#define EPSF 1e-10f

// Packed per-thread counters: pred count bits [0,10), tgt count bits [10,20),
// tp count bits [20,32). Each thread processes exactly 32 elements -> each
// field <= 32, far below overflow.
__global__ __launch_bounds__(THREADS) void dice_hist(
    const int* __restrict__ pred, const int* __restrict__ tgt,
    unsigned int* __restrict__ gcounts, int n4_total)
{
    __shared__ unsigned int h[THREADS * STRIDE];
    const int tid = threadIdx.x;
    const unsigned base = tid * STRIDE;

    #pragma unroll
    for (int c = 0; c < STRIDE; ++c) h[base + c] = 0u;
    // No sync needed: slots are thread-private until the reduction.

    const long long gt = (long long)blockIdx.x * THREADS + tid;
    const long long nThreads = (long long)BLOCKS * THREADS;
    const int4* p4 = (const int4*)pred;
    const int4* t4 = (const int4*)tgt;

    for (long long i = gt; i < n4_total; i += nThreads) {
        int4 p = p4[i];
        int4 t = t4[i];
        #define PAIR(pp, tt)                                                   \
            atomicAdd(&h[base + (unsigned)(pp)],                               \
                      ((pp) == (tt)) ? 0x100001u : 1u);                        \
            atomicAdd(&h[base + (unsigned)(tt)], 1024u);
        PAIR(p.x, t.x)
        PAIR(p.y, t.y)
        PAIR(p.z, t.z)
        PAIR(p.w, t.w)
        #undef PAIR
    }

    __syncthreads();

    // Block reduction: 8 partial sums per class (20 classes -> 160 threads).
    if (tid < 8 * NC) {
        const int c   = tid >> 3;   // class 0..19
        const int sub = tid & 7;    // partial 0..7, 32 thread-slots each
        unsigned sp = 0, st = 0, stp = 0;
        const int k0 = sub * 32;
        #pragma unroll
        for (int k = 0; k < 32; ++k) {
            unsigned v = h[(k0 + k) * STRIDE + c];
            sp  += v & 1023u;
            st  += (v >> 10) & 1023u;
            stp += v >> 20;
        }
        // Combine the 8 partials (groups of 8 lanes, aligned within waves).
        #pragma unroll
        for (int d = 4; d >= 1; d >>= 1) {
            sp  += __shfl_down(sp,  d, 8);
            st  += __shfl_down(st,  d, 8);
            stp += __shfl_down(stp, d, 8);
        }
        if (sub == 0) {
            atomicAdd(&gcounts[c],          sp);
            atomicAdd(&gcounts[NC + c],     st);
            atomicAdd(&gcounts[2 * NC + c], stp);
        }
    }
}

__global__ void dice_final(const unsigned int* __restrict__ gcounts,
                           float* __restrict__ out)
{
    const int c = threadIdx.x;  // 64 lanes, classes 1..19 contribute
    float contrib = 0.0f;
    if (c >= 1 && c < NC) {
        float tp = (float)gcounts[2 * NC + c];
        float pc = (float)gcounts[c];
        float tc = (float)gcounts[NC + c];
        contrib = 2.0f * tp / (pc + tc + EPSF);
    }
    #pragma unroll
    for (int d = 32; d >= 1; d >>= 1) contrib += __shfl_down(contrib, d, 64);
    if (c == 0) out[0] = contrib * (1.0f / 19.0f);
}

extern "C" void kernel_launch(void* const* d_in, const int* in_sizes, int n_in,
                              void* d_out, int out_size, void* d_ws, size_t ws_size,
                              hipStream_t stream) {
    const int* pred = (const int*)d_in[0];
    const int* tgt  = (const int*)d_in[1];
    unsigned int* gcounts = (unsigned int*)d_ws;

    // d_ws is NOT re-poisoned between replays -> zero the 60 counters each call.
    hipMemsetAsync(d_ws, 0, 3 * NC * sizeof(unsigned int), stream);

    const int n  = in_sizes[0];        // 16,777,216 (divisible by 4)
    const int n4 = n >> 2;

    dice_hist<<<BLOCKS, THREADS, 0, stream>>>(pred, tgt, gcounts, n4);
    dice_final<<<1, 64, 0, stream>>>(gcounts, (float*)d_out);
}